// Round 3
// baseline (264.622 us; speedup 1.0000x reference)
//
#include <hip/hip_runtime.h>
#include <math.h>

#define NB    16
#define CIN   64
#define COUT  64
#define NN    16384
#define HH    8192
#define MODES 2048
#define TEMBD 512

// XOR bank swizzle: bijection on [0,8192); makes stride-32 and contiguous-32
// per-thread LDS access patterns conflict-free without padding (LDS stays 64 KiB).
__device__ __forceinline__ int swz(int e) { return e ^ ((e >> 5) & 31); }
__device__ __forceinline__ int rev13(int x) { return (int)(__brev((unsigned)x) >> 19); }

// async global->LDS, 16B per lane: LDS dest = wave-uniform base + lane*16,
// global src is per-lane.
__device__ __forceinline__ void gl_lds16(const void* gsrc, void* lds) {
  __builtin_amdgcn_global_load_lds(
      (const __attribute__((address_space(1))) void*)gsrc,
      (__attribute__((address_space(3))) void*)lds, 16, 0, 0);
}

__global__ void init_tw_k(float2* __restrict__ tw8, float2* __restrict__ tw16) {
  int j = blockIdx.x * blockDim.x + threadIdx.x;
  if (j < 4096) {
    double a = (2.0 * 3.14159265358979323846 / 8192.0) * (double)j;
    tw8[j] = make_float2((float)cos(a), (float)sin(a));
  }
  if (j < 2048) {
    double a = (2.0 * 3.14159265358979323846 / 16384.0) * (double)j;
    tw16[j] = make_float2((float)cos(a), (float)sin(a));
  }
}

// In-register DIF pass: elements e_j = base + j*S (j=0..J-1), stages lh = LH_HI
// down; pbase = base mod h (constant across the pass's stages by construction).
template<int J, int S, int LH_HI>
__device__ __forceinline__ void pass_dif(float* zr, float* zi, int pbase,
                                         const float2* __restrict__ tw) {
  int lh = LH_HI;
#pragma unroll
  for (int half = J / 2; half >= 1; half >>= 1, --lh) {
#pragma unroll
    for (int blk = 0; blk < J; blk += 2 * half) {
#pragma unroll
      for (int q = 0; q < half; ++q) {
        const int j0 = blk + q, j1 = j0 + half;
        const float2 w = tw[(pbase + q * S) << (12 - lh)];
        const float ur = zr[j0], ui = zi[j0];
        const float vr = zr[j1], vi = zi[j1];
        zr[j0] = ur + vr; zi[j0] = ui + vi;
        const float br = ur - vr, bi = ui - vi;
        zr[j1] = br * w.x + bi * w.y;   // *(c - i s)
        zi[j1] = bi * w.x - br * w.y;
      }
    }
  }
}

// In-register DIT pass (e^{+i}): stages lh = LH_LO up.
template<int J, int S, int LH_LO>
__device__ __forceinline__ void pass_dit(float* zr, float* zi, int pbase,
                                         const float2* __restrict__ tw) {
  int lh = LH_LO;
#pragma unroll
  for (int half = 1; half <= J / 2; half <<= 1, ++lh) {
#pragma unroll
    for (int blk = 0; blk < J; blk += 2 * half) {
#pragma unroll
      for (int q = 0; q < half; ++q) {
        const int j0 = blk + q, j1 = j0 + half;
        const float2 w = tw[(pbase + q * S) << (12 - lh)];
        const float vr = zr[j1], vi = zi[j1];
        const float tr = vr * w.x - vi * w.y;  // *(c + i s)
        const float ti = vr * w.y + vi * w.x;
        const float ur = zr[j0], ui = zi[j0];
        zr[j0] = ur + tr; zi[j0] = ui + ti;
        zr[j1] = ur - tr; zi[j1] = ui - ti;
      }
    }
  }
}

// Forward: one block per (b, c_in) row. Pack-trick rfft via 8192-pt complex DIF
// FFT: 3 register passes (4+4+5 stages), 3 LDS round-trips. Fused temb scalar.
__global__ __launch_bounds__(256) void fwd_fft_k(
    const float* __restrict__ x, const float* __restrict__ temb,
    const float* __restrict__ dw, const float* __restrict__ db,
    const float2* __restrict__ tw8, const float2* __restrict__ tw16,
    float2* __restrict__ xm)
{
  __shared__ float re[HH];
  __shared__ float im[HH];
  const int row = blockIdx.x;          // b*64 + ci
  const int b = row >> 6, ci = row & 63;
  const int tid = threadIdx.x;

  // t = silu(temb[b]) . dw[ci] + db[ci]  (block-cooperative 512-dot)
  float part = 0.f;
  {
    const float* tb = temb + b * TEMBD;
    const float* wrow = dw + ci * TEMBD;
    for (int j = tid; j < TEMBD; j += 256) {
      float v = tb[j];
      part += v * wrow[j] / (1.f + __expf(-v));
    }
    for (int off = 32; off > 0; off >>= 1) part += __shfl_down(part, off, 64);
    if ((tid & 63) == 0) re[tid >> 6] = part;
  }
  __syncthreads();
  const float tval = re[0] + re[1] + re[2] + re[3] + db[ci];
  __syncthreads();

  float zr[32], zi[32];

  // P1: global (packed z[m] = x[2m] + i x[2m+1]) -> regs, stages lh=12..9, -> LDS
  const float2* xr = (const float2*)(x + (size_t)row * NN);
#pragma unroll
  for (int g = 0; g < 2; ++g) {
    const int i0 = tid + g * 256;
#pragma unroll
    for (int j = 0; j < 16; ++j) {
      float2 v = xr[i0 + j * 512];
      zr[g * 16 + j] = v.x; zi[g * 16 + j] = v.y;
    }
  }
#pragma unroll
  for (int g = 0; g < 2; ++g) {
    const int i0 = tid + g * 256;
    pass_dif<16, 512, 12>(zr + g * 16, zi + g * 16, i0, tw8);
#pragma unroll
    for (int j = 0; j < 16; ++j) {
      const int e = swz(i0 + j * 512);
      re[e] = zr[g * 16 + j]; im[e] = zi[g * 16 + j];
    }
  }
  __syncthreads();

  // P2: stride-32 groups, stages lh=8..5
  {
    const int r = tid & 31;
#pragma unroll
    for (int g = 0; g < 2; ++g) {
      const int base = ((tid >> 5) + g * 8) * 512 + r;
#pragma unroll
      for (int j = 0; j < 16; ++j) {
        const int e = swz(base + j * 32);
        zr[g * 16 + j] = re[e]; zi[g * 16 + j] = im[e];
      }
      pass_dif<16, 32, 8>(zr + g * 16, zi + g * 16, r, tw8);
#pragma unroll
      for (int j = 0; j < 16; ++j) {
        const int e = swz(base + j * 32);
        re[e] = zr[g * 16 + j]; im[e] = zi[g * 16 + j];
      }
    }
  }
  __syncthreads();

  // P3: contiguous-32 groups, stages lh=4..0. The unpack phase only reads
  // logical positions ≡0,3 (mod 4) (rev13(k)&3==0 for k<2048, ==3 for H-k),
  // so skip the other stores; DCE then deletes the dead last-stage work.
  {
    const int base = tid * 32;
#pragma unroll
    for (int j = 0; j < 32; ++j) {
      const int e = swz(base + j);
      zr[j] = re[e]; zi[j] = im[e];
    }
    pass_dif<32, 1, 4>(zr, zi, 0, tw8);
#pragma unroll
    for (int j = 0; j < 32; ++j) {
      if ((j & 3) == 1 || (j & 3) == 2) continue;
      const int e = swz(base + j);
      re[e] = zr[j]; im[e] = zi[j];
    }
  }
  __syncthreads();

  // unpack X[k] = 0.5(A+conj(B)) - 0.5 i e^{-2pi i k/N} (A-conj(B)); A=Zf[k], B=Zf[H-k]
  float2* xrow = xm + (size_t)row * MODES;
  for (int k = tid; k < MODES; k += 256) {
    const int ka = swz(rev13(k));
    const int kb = swz(rev13((HH - k) & (HH - 1)));
    float Ar = re[ka], Ai = im[ka];
    float Br = re[kb], Bi = -im[kb];
    float Sr = 0.5f * (Ar + Br), Si = 0.5f * (Ai + Bi);
    float Dr = 0.5f * (Ar - Br), Di = 0.5f * (Ai - Bi);
    float2 wv = tw16[k];
    float c = wv.x, s = wv.y;
    float Xr = Sr - s * Dr + c * Di;
    float Xi = Si - s * Di - c * Dr;
    xrow[k] = make_float2(Xr + tval, Xi);
  }
}

// out_m[b,o,m] = sum_i xm[b,i,m] * (wr[i,o,m] + i wi[i,o,m])
//
// Register-tiled: thread = (mp, og, h) computes 4 b x 2 o x 2 m accumulators
// (16 cmul per i from 6 ds_read_b128: 2.7x better FMA/LDS than prior version).
// Block = 16 b x 16 o x 16 m tile; i in 8 chunks of 8, double-buffered LDS
// (64 KiB total), T14 async-stage split: issue loads -> compute -> ds_write.
// w is read globally exactly once (o,m tiles partition it); xm is L3-resident.
__global__ __launch_bounds__(256) void spec_mul_k(
    const float2* __restrict__ xm, const float* __restrict__ wr,
    const float* __restrict__ wi, float2* __restrict__ om)
{
  __shared__ float2 xs[2][128 * 16];   // [buf][b*8+il][m] : 16 KiB each
  __shared__ float4 wsh[2][1024];      // [buf][il*128+oo*64+og*8+mp] : 16 KiB each

  const int tid = threadIdx.x;
  const int mp = tid & 7;              // mode-pair within tile
  const int og = (tid >> 3) & 7;       // o-pair group
  const int h  = tid >> 6;             // b-quarter == wave id
  const int ln = tid & 63;

  const int m0 = blockIdx.x * 16;
  const int o0 = blockIdx.y * 16;

  float4 acc[4][2];
#pragma unroll
  for (int j = 0; j < 4; ++j) {
    acc[j][0] = make_float4(0.f, 0.f, 0.f, 0.f);
    acc[j][1] = make_float4(0.f, 0.f, 0.f, 0.f);
  }

  float2 wrv[4], wiv[4];

  // ---- staging helpers ----
  // xs rows r = b*8+il (128 rows of 16 float2 = 128 B); wave h, call t covers
  // rows h*32 + t*8 .. +8 linearly (gl_lds dest = uniform base + lane*16).
#define STAGE_X(ic, buf)                                                      \
  {                                                                           \
    _Pragma("unroll")                                                         \
    for (int t = 0; t < 4; ++t) {                                             \
      const int r = h * 32 + t * 8 + (ln >> 3);                               \
      const int b = r >> 3, il = r & 7;                                       \
      const float2* src =                                                     \
          xm + ((size_t)(b * CIN + (ic) * 8 + il)) * MODES + m0 + (ln & 7) * 2;\
      gl_lds16((const void*)src, (void*)((char*)&xs[buf][0] + (h * 4 + t) * 1024)); \
    }                                                                         \
  }

#define W_LOAD(ic)                                                            \
  {                                                                           \
    _Pragma("unroll")                                                         \
    for (int t = 0; t < 4; ++t) {                                             \
      const int e = tid + t * 256;                                            \
      const int il = e >> 7, oo = (e >> 6) & 1, g2 = (e >> 3) & 7, ep = e & 7;\
      const int o = g2 * 2 + oo;                                              \
      const size_t wb =                                                       \
          ((size_t)(((ic) * 8 + il) * COUT + o0 + o)) * MODES + m0 + ep * 2;  \
      wrv[t] = *(const float2*)(wr + wb);                                     \
      wiv[t] = *(const float2*)(wi + wb);                                     \
    }                                                                         \
  }

#define W_WRITE(buf)                                                          \
  {                                                                           \
    _Pragma("unroll")                                                         \
    for (int t = 0; t < 4; ++t)                                               \
      wsh[buf][tid + t * 256] =                                               \
          make_float4(wrv[t].x, wrv[t].y, wiv[t].x, wiv[t].y);                \
  }

  // prologue: fill buffer 0
  STAGE_X(0, 0);
  W_LOAD(0);
  W_WRITE(0);
  __syncthreads();

  for (int ic = 0; ic < 8; ++ic) {
    const int buf = ic & 1;
    if (ic < 7) {
      STAGE_X(ic + 1, buf ^ 1);   // async gl_lds into other buffer
      W_LOAD(ic + 1);             // issue w loads to regs (hide under compute)
    }
    // ---- compute 8 i's from buf ----
#pragma unroll
    for (int il = 0; il < 8; ++il) {
      const float4 wA = wsh[buf][il * 128 + og * 8 + mp];
      const float4 wB = wsh[buf][il * 128 + 64 + og * 8 + mp];
#pragma unroll
      for (int j = 0; j < 4; ++j) {
        const float4 xv = *(const float4*)&xs[buf][((h * 4 + j) * 8 + il) * 16 + mp * 2];
        acc[j][0].x += xv.x * wA.x - xv.y * wA.z;
        acc[j][0].y += xv.x * wA.z + xv.y * wA.x;
        acc[j][0].z += xv.z * wA.y - xv.w * wA.w;
        acc[j][0].w += xv.z * wA.w + xv.w * wA.y;
        acc[j][1].x += xv.x * wB.x - xv.y * wB.z;
        acc[j][1].y += xv.x * wB.z + xv.y * wB.x;
        acc[j][1].z += xv.z * wB.y - xv.w * wB.w;
        acc[j][1].w += xv.z * wB.w + xv.w * wB.y;
      }
    }
    if (ic < 7) W_WRITE(buf ^ 1);  // w regs -> LDS after compute (T14 split)
    __syncthreads();               // drains gl_lds vmcnt + ds lgkm
  }

#pragma unroll
  for (int j = 0; j < 4; ++j) {
    const int b = h * 4 + j;
#pragma unroll
    for (int oo = 0; oo < 2; ++oo) {
      const int o = o0 + og * 2 + oo;
      *(float4*)(om + ((size_t)(b * COUT + o)) * MODES + m0 + mp * 2) = acc[j][oo];
    }
  }
#undef STAGE_X
#undef W_LOAD
#undef W_WRITE
}

// Inverse: one block per (b, c_out) row. Packed half-spectrum scatter (bit-rev
// positions), then 3 register DIT passes; pass 3 stores straight to global.
__global__ __launch_bounds__(256) void inv_fft_k(
    const float2* __restrict__ om, const float2* __restrict__ tw8,
    const float2* __restrict__ tw16, float* __restrict__ out)
{
  __shared__ float re[HH];
  __shared__ float im[HH];
  const int row = blockIdx.x;   // b*64 + o
  const int tid = threadIdx.x;

  for (int q = tid; q < HH; q += 256) { re[q] = 0.f; im[q] = 0.f; }
  __syncthreads();

  const float2* grow = om + (size_t)row * MODES;
  for (int k = tid; k < MODES; k += 256) {
    float2 g = grow[k];
    if (k == 0) {
      float v = 0.5f * g.x;        // Zb[0] = 0.5*Re(G0)*(1+i)
      re[0] = v; im[0] = v;
    } else {
      // P = 0.5 G[k]; s = i w P, w = e^{+2pi i k/N}; Zb[k]=P+s, Zb[H-k]=conj(P-s)
      float2 wv = tw16[k];
      float Pr = 0.5f * g.x, Pi = 0.5f * g.y;
      float c = wv.x, s = wv.y;
      float sr = -(c * Pi + s * Pr);
      float si =  (c * Pr - s * Pi);
      int ka = swz(rev13(k));
      int kb = swz(rev13(HH - k));
      re[ka] = Pr + sr; im[ka] = Pi + si;
      re[kb] = Pr - sr; im[kb] = -(Pi - si);
    }
  }
  __syncthreads();

  float zr[32], zi[32];

  // P1: contiguous-32 groups, stages lh=0..4
  {
    const int base = tid * 32;
#pragma unroll
    for (int j = 0; j < 32; ++j) {
      const int e = swz(base + j);
      zr[j] = re[e]; zi[j] = im[e];
    }
    pass_dit<32, 1, 0>(zr, zi, 0, tw8);
#pragma unroll
    for (int j = 0; j < 32; ++j) {
      const int e = swz(base + j);
      re[e] = zr[j]; im[e] = zi[j];
    }
  }
  __syncthreads();

  // P2: stride-32 groups, stages lh=5..8
  {
    const int r = tid & 31;
#pragma unroll
    for (int g = 0; g < 2; ++g) {
      const int base = ((tid >> 5) + g * 8) * 512 + r;
#pragma unroll
      for (int j = 0; j < 16; ++j) {
        const int e = swz(base + j * 32);
        zr[g * 16 + j] = re[e]; zi[g * 16 + j] = im[e];
      }
      pass_dit<16, 32, 5>(zr + g * 16, zi + g * 16, r, tw8);
#pragma unroll
      for (int j = 0; j < 16; ++j) {
        const int e = swz(base + j * 32);
        re[e] = zr[g * 16 + j]; im[e] = zi[g * 16 + j];
      }
    }
  }
  __syncthreads();

  // P3: stride-512 groups, stages lh=9..12; write x[2m],x[2m+1] as float2
  {
    float2* orow = (float2*)(out + (size_t)row * NN);
    const float sc = 1.0f / 8192.0f;
#pragma unroll
    for (int g = 0; g < 2; ++g) {
      const int i0 = tid + g * 256;
#pragma unroll
      for (int j = 0; j < 16; ++j) {
        const int e = swz(i0 + j * 512);
        zr[g * 16 + j] = re[e]; zi[g * 16 + j] = im[e];
      }
      pass_dit<16, 512, 9>(zr + g * 16, zi + g * 16, i0, tw8);
#pragma unroll
      for (int j = 0; j < 16; ++j) {
        orow[i0 + j * 512] = make_float2(zr[g * 16 + j] * sc, zi[g * 16 + j] * sc);
      }
    }
  }
}

extern "C" void kernel_launch(void* const* d_in, const int* in_sizes, int n_in,
                              void* d_out, int out_size, void* d_ws, size_t ws_size,
                              hipStream_t stream) {
  const float* x    = (const float*)d_in[0];
  const float* temb = (const float*)d_in[1];
  const float* wr   = (const float*)d_in[2];
  const float* wi   = (const float*)d_in[3];
  const float* dw   = (const float*)d_in[4];
  const float* db   = (const float*)d_in[5];
  float* out = (float*)d_out;

  char* ws = (char*)d_ws;
  float2* tw8  = (float2*)ws;                               // 32 KiB
  float2* tw16 = (float2*)(ws + 32768);                     // 16 KiB
  float2* xm   = (float2*)(ws + 65536);                     // 16 MiB
  float2* om   = (float2*)(ws + 65536 + (size_t)16777216);  // 16 MiB

  hipLaunchKernelGGL(init_tw_k, dim3(16), dim3(256), 0, stream, tw8, tw16);
  hipLaunchKernelGGL(fwd_fft_k, dim3(NB * CIN), dim3(256), 0, stream,
                     x, temb, dw, db, tw8, tw16, xm);
  hipLaunchKernelGGL(spec_mul_k, dim3(MODES / 16, COUT / 16), dim3(256), 0, stream,
                     xm, wr, wi, om);
  hipLaunchKernelGGL(inv_fft_k, dim3(NB * COUT), dim3(256), 0, stream,
                     om, tw8, tw16, out);
}

// Round 4
// 254.536 us; speedup vs baseline: 1.0396x; 1.0396x over previous
//
#include <hip/hip_runtime.h>
#include <math.h>

#define NB    16
#define CIN   64
#define COUT  64
#define NN    16384
#define HH    8192
#define MODES 2048
#define TEMBD 512

// XOR bank swizzle: bijection on [0,8192); makes stride-32 and contiguous-32
// per-thread LDS access patterns conflict-free without padding (LDS stays 64 KiB).
__device__ __forceinline__ int swz(int e) { return e ^ ((e >> 5) & 31); }
__device__ __forceinline__ int rev13(int x) { return (int)(__brev((unsigned)x) >> 19); }

// async global->LDS, 16B per lane: LDS dest = wave-uniform base + lane*16,
// global src is per-lane.
__device__ __forceinline__ void gl_lds16(const void* gsrc, void* lds) {
  __builtin_amdgcn_global_load_lds(
      (const __attribute__((address_space(1))) void*)gsrc,
      (__attribute__((address_space(3))) void*)lds, 16, 0, 0);
}

__global__ void init_tw_k(float2* __restrict__ tw8, float2* __restrict__ tw16) {
  int j = blockIdx.x * blockDim.x + threadIdx.x;
  if (j < 4096) {
    double a = (2.0 * 3.14159265358979323846 / 8192.0) * (double)j;
    tw8[j] = make_float2((float)cos(a), (float)sin(a));
  }
  if (j < 2048) {
    double a = (2.0 * 3.14159265358979323846 / 16384.0) * (double)j;
    tw16[j] = make_float2((float)cos(a), (float)sin(a));
  }
}

// In-register DIF pass: elements e_j = base + j*S (j=0..J-1), stages lh = LH_HI
// down; pbase = base mod h (constant across the pass's stages by construction).
template<int J, int S, int LH_HI>
__device__ __forceinline__ void pass_dif(float* zr, float* zi, int pbase,
                                         const float2* __restrict__ tw) {
  int lh = LH_HI;
#pragma unroll
  for (int half = J / 2; half >= 1; half >>= 1, --lh) {
#pragma unroll
    for (int blk = 0; blk < J; blk += 2 * half) {
#pragma unroll
      for (int q = 0; q < half; ++q) {
        const int j0 = blk + q, j1 = j0 + half;
        const float2 w = tw[(pbase + q * S) << (12 - lh)];
        const float ur = zr[j0], ui = zi[j0];
        const float vr = zr[j1], vi = zi[j1];
        zr[j0] = ur + vr; zi[j0] = ui + vi;
        const float br = ur - vr, bi = ui - vi;
        zr[j1] = br * w.x + bi * w.y;   // *(c - i s)
        zi[j1] = bi * w.x - br * w.y;
      }
    }
  }
}

// In-register DIT pass (e^{+i}): stages lh = LH_LO up.
template<int J, int S, int LH_LO>
__device__ __forceinline__ void pass_dit(float* zr, float* zi, int pbase,
                                         const float2* __restrict__ tw) {
  int lh = LH_LO;
#pragma unroll
  for (int half = 1; half <= J / 2; half <<= 1, ++lh) {
#pragma unroll
    for (int blk = 0; blk < J; blk += 2 * half) {
#pragma unroll
      for (int q = 0; q < half; ++q) {
        const int j0 = blk + q, j1 = j0 + half;
        const float2 w = tw[(pbase + q * S) << (12 - lh)];
        const float vr = zr[j1], vi = zi[j1];
        const float tr = vr * w.x - vi * w.y;  // *(c + i s)
        const float ti = vr * w.y + vi * w.x;
        const float ur = zr[j0], ui = zi[j0];
        zr[j0] = ur + tr; zi[j0] = ui + ti;
        zr[j1] = ur - tr; zi[j1] = ui - ti;
      }
    }
  }
}

// Forward: one block per (b, c_in) row. Pack-trick rfft via 8192-pt complex DIF
// FFT: 3 register passes (4+4+5 stages), 3 LDS round-trips. Fused temb scalar.
__global__ __launch_bounds__(256) void fwd_fft_k(
    const float* __restrict__ x, const float* __restrict__ temb,
    const float* __restrict__ dw, const float* __restrict__ db,
    const float2* __restrict__ tw8, const float2* __restrict__ tw16,
    float2* __restrict__ xm)
{
  __shared__ float re[HH];
  __shared__ float im[HH];
  const int row = blockIdx.x;          // b*64 + ci
  const int b = row >> 6, ci = row & 63;
  const int tid = threadIdx.x;

  // t = silu(temb[b]) . dw[ci] + db[ci]  (block-cooperative 512-dot)
  float part = 0.f;
  {
    const float* tb = temb + b * TEMBD;
    const float* wrow = dw + ci * TEMBD;
    for (int j = tid; j < TEMBD; j += 256) {
      float v = tb[j];
      part += v * wrow[j] / (1.f + __expf(-v));
    }
    for (int off = 32; off > 0; off >>= 1) part += __shfl_down(part, off, 64);
    if ((tid & 63) == 0) re[tid >> 6] = part;
  }
  __syncthreads();
  const float tval = re[0] + re[1] + re[2] + re[3] + db[ci];
  __syncthreads();

  float zr[32], zi[32];

  // P1: global (packed z[m] = x[2m] + i x[2m+1]) -> regs, stages lh=12..9, -> LDS
  const float2* xr = (const float2*)(x + (size_t)row * NN);
#pragma unroll
  for (int g = 0; g < 2; ++g) {
    const int i0 = tid + g * 256;
#pragma unroll
    for (int j = 0; j < 16; ++j) {
      float2 v = xr[i0 + j * 512];
      zr[g * 16 + j] = v.x; zi[g * 16 + j] = v.y;
    }
  }
#pragma unroll
  for (int g = 0; g < 2; ++g) {
    const int i0 = tid + g * 256;
    pass_dif<16, 512, 12>(zr + g * 16, zi + g * 16, i0, tw8);
#pragma unroll
    for (int j = 0; j < 16; ++j) {
      const int e = swz(i0 + j * 512);
      re[e] = zr[g * 16 + j]; im[e] = zi[g * 16 + j];
    }
  }
  __syncthreads();

  // P2: stride-32 groups, stages lh=8..5
  {
    const int r = tid & 31;
#pragma unroll
    for (int g = 0; g < 2; ++g) {
      const int base = ((tid >> 5) + g * 8) * 512 + r;
#pragma unroll
      for (int j = 0; j < 16; ++j) {
        const int e = swz(base + j * 32);
        zr[g * 16 + j] = re[e]; zi[g * 16 + j] = im[e];
      }
      pass_dif<16, 32, 8>(zr + g * 16, zi + g * 16, r, tw8);
#pragma unroll
      for (int j = 0; j < 16; ++j) {
        const int e = swz(base + j * 32);
        re[e] = zr[g * 16 + j]; im[e] = zi[g * 16 + j];
      }
    }
  }
  __syncthreads();

  // P3: contiguous-32 groups, stages lh=4..0. The unpack phase only reads
  // logical positions ≡0,3 (mod 4) (rev13(k)&3==0 for k<2048, ==3 for H-k),
  // so skip the other stores; DCE then deletes the dead last-stage work.
  {
    const int base = tid * 32;
#pragma unroll
    for (int j = 0; j < 32; ++j) {
      const int e = swz(base + j);
      zr[j] = re[e]; zi[j] = im[e];
    }
    pass_dif<32, 1, 4>(zr, zi, 0, tw8);
#pragma unroll
    for (int j = 0; j < 32; ++j) {
      if ((j & 3) == 1 || (j & 3) == 2) continue;
      const int e = swz(base + j);
      re[e] = zr[j]; im[e] = zi[j];
    }
  }
  __syncthreads();

  // unpack X[k] = 0.5(A+conj(B)) - 0.5 i e^{-2pi i k/N} (A-conj(B)); A=Zf[k], B=Zf[H-k]
  float2* xrow = xm + (size_t)row * MODES;
  for (int k = tid; k < MODES; k += 256) {
    const int ka = swz(rev13(k));
    const int kb = swz(rev13((HH - k) & (HH - 1)));
    float Ar = re[ka], Ai = im[ka];
    float Br = re[kb], Bi = -im[kb];
    float Sr = 0.5f * (Ar + Br), Si = 0.5f * (Ai + Bi);
    float Dr = 0.5f * (Ar - Br), Di = 0.5f * (Ai - Bi);
    float2 wv = tw16[k];
    float c = wv.x, s = wv.y;
    float Xr = Sr - s * Dr + c * Di;
    float Xi = Si - s * Di - c * Dr;
    xrow[k] = make_float2(Xr + tval, Xi);
  }
}

// out_m[b,o,m] = sum_i xm[b,i,m] * (wr[i,o,m] + i wi[i,o,m])
//
// Occupancy-first redesign (R3 lesson: occupancy > LDS-instruction count).
// Grid 1024 blocks (4 blocks/CU = 16 waves/CU = 50%), 256 thr, 24 KiB LDS,
// low VGPR (no held prefetch regs). Tile = 16b x 8o x 16m; thread =
// (mm 0..15, og 0..3, h 0..3) computes 4b x 2o x 1m (acc = 16 floats).
// w transposed into [il][m][o-pair] float2 planes so inner loop reads w as
// 2 x ds_read_b64 at the bank-BW floor; x reads are 4 x b64 broadcast.
// 6 LDS reads : 32 FMA per il. w read globally exactly once.
__global__ __launch_bounds__(256) void spec_mul_k(
    const float2* __restrict__ xm, const float* __restrict__ wr,
    const float* __restrict__ wi, float2* __restrict__ om)
{
  __shared__ float2 xs[128 * 16];     // [b*8+il][mm]                16 KiB
  __shared__ float2 wsr[8 * 16 * 4];  // [il][mm][og] {wr(2og),wr(2og+1)} 4 KiB
  __shared__ float2 wsi[8 * 16 * 4];  // same for wi                  4 KiB

  const int tid = threadIdx.x;
  const int mm = tid & 15;
  const int og = (tid >> 4) & 3;
  const int h  = tid >> 6;            // wave id = b-quad
  const int ln = tid & 63;

  const int m0 = blockIdx.x * 16;
  const int o0 = blockIdx.y * 8;

  float2 acc[4][2];
#pragma unroll
  for (int j = 0; j < 4; ++j) {
    acc[j][0] = make_float2(0.f, 0.f);
    acc[j][1] = make_float2(0.f, 0.f);
  }

  for (int ic = 0; ic < 8; ++ic) {
    // ---- stage xs: 128 rows (b*8+il) of 16 float2 via gl_lds (linear) ----
#pragma unroll
    for (int t = 0; t < 4; ++t) {
      const int r = h * 32 + t * 8 + (ln >> 3);   // row = b*8+il
      const int b = r >> 3, il = r & 7;
      const float2* src =
          xm + ((size_t)(b * CIN + ic * 8 + il)) * MODES + m0 + (ln & 7) * 2;
      gl_lds16((const void*)src, (void*)((char*)xs + (h * 32 + t * 8) * 128));
    }
    // ---- stage w: transpose [i][o][m] -> [il][mm][og] o-pair float2 ----
    // lanes: mm fast => coalesced 64-B segments; 2 entries/thread/plane.
#pragma unroll
    for (int t = 0; t < 2; ++t) {
      const int f = tid + t * 256;                // 0..511
      const int fm = f & 15, fg = (f >> 4) & 3, fil = f >> 6;
      const size_t rA =
          ((size_t)((ic * 8 + fil) * COUT + o0 + fg * 2)) * MODES + m0 + fm;
      const size_t rB = rA + MODES;
      wsr[(fil * 16 + fm) * 4 + fg] = make_float2(wr[rA], wr[rB]);
      wsi[(fil * 16 + fm) * 4 + fg] = make_float2(wi[rA], wi[rB]);
    }
    __syncthreads();   // drains gl_lds vmcnt + ds writes

    // ---- compute 8 i's: per il, 2 w-b64 + 4 x-b64 (broadcast) + 32 FMA ----
#pragma unroll
    for (int il = 0; il < 8; ++il) {
      const float2 wrp = wsr[(il * 16 + mm) * 4 + og];
      const float2 wip = wsi[(il * 16 + mm) * 4 + og];
#pragma unroll
      for (int j = 0; j < 4; ++j) {
        const float2 xv = xs[((h * 4 + j) * 8 + il) * 16 + mm];
        acc[j][0].x += xv.x * wrp.x - xv.y * wip.x;
        acc[j][0].y += xv.x * wip.x + xv.y * wrp.x;
        acc[j][1].x += xv.x * wrp.y - xv.y * wip.y;
        acc[j][1].y += xv.x * wip.y + xv.y * wrp.y;
      }
    }
    if (ic < 7) __syncthreads();
  }

#pragma unroll
  for (int j = 0; j < 4; ++j) {
    const int b = h * 4 + j;
    const size_t ob = ((size_t)(b * COUT + o0 + og * 2)) * MODES + m0 + mm;
    om[ob] = acc[j][0];
    om[ob + MODES] = acc[j][1];
  }
}

// Inverse: one block per (b, c_out) row. Packed half-spectrum scatter (bit-rev
// positions), then 3 register DIT passes; pass 3 stores straight to global.
__global__ __launch_bounds__(256) void inv_fft_k(
    const float2* __restrict__ om, const float2* __restrict__ tw8,
    const float2* __restrict__ tw16, float* __restrict__ out)
{
  __shared__ float re[HH];
  __shared__ float im[HH];
  const int row = blockIdx.x;   // b*64 + o
  const int tid = threadIdx.x;

  for (int q = tid; q < HH; q += 256) { re[q] = 0.f; im[q] = 0.f; }
  __syncthreads();

  const float2* grow = om + (size_t)row * MODES;
  for (int k = tid; k < MODES; k += 256) {
    float2 g = grow[k];
    if (k == 0) {
      float v = 0.5f * g.x;        // Zb[0] = 0.5*Re(G0)*(1+i)
      re[0] = v; im[0] = v;
    } else {
      // P = 0.5 G[k]; s = i w P, w = e^{+2pi i k/N}; Zb[k]=P+s, Zb[H-k]=conj(P-s)
      float2 wv = tw16[k];
      float Pr = 0.5f * g.x, Pi = 0.5f * g.y;
      float c = wv.x, s = wv.y;
      float sr = -(c * Pi + s * Pr);
      float si =  (c * Pr - s * Pi);
      int ka = swz(rev13(k));
      int kb = swz(rev13(HH - k));
      re[ka] = Pr + sr; im[ka] = Pi + si;
      re[kb] = Pr - sr; im[kb] = -(Pi - si);
    }
  }
  __syncthreads();

  float zr[32], zi[32];

  // P1: contiguous-32 groups, stages lh=0..4
  {
    const int base = tid * 32;
#pragma unroll
    for (int j = 0; j < 32; ++j) {
      const int e = swz(base + j);
      zr[j] = re[e]; zi[j] = im[e];
    }
    pass_dit<32, 1, 0>(zr, zi, 0, tw8);
#pragma unroll
    for (int j = 0; j < 32; ++j) {
      const int e = swz(base + j);
      re[e] = zr[j]; im[e] = zi[j];
    }
  }
  __syncthreads();

  // P2: stride-32 groups, stages lh=5..8
  {
    const int r = tid & 31;
#pragma unroll
    for (int g = 0; g < 2; ++g) {
      const int base = ((tid >> 5) + g * 8) * 512 + r;
#pragma unroll
      for (int j = 0; j < 16; ++j) {
        const int e = swz(base + j * 32);
        zr[g * 16 + j] = re[e]; zi[g * 16 + j] = im[e];
      }
      pass_dit<16, 32, 5>(zr + g * 16, zi + g * 16, r, tw8);
#pragma unroll
      for (int j = 0; j < 16; ++j) {
        const int e = swz(base + j * 32);
        re[e] = zr[g * 16 + j]; im[e] = zi[g * 16 + j];
      }
    }
  }
  __syncthreads();

  // P3: stride-512 groups, stages lh=9..12; write x[2m],x[2m+1] as float2
  {
    float2* orow = (float2*)(out + (size_t)row * NN);
    const float sc = 1.0f / 8192.0f;
#pragma unroll
    for (int g = 0; g < 2; ++g) {
      const int i0 = tid + g * 256;
#pragma unroll
      for (int j = 0; j < 16; ++j) {
        const int e = swz(i0 + j * 512);
        zr[g * 16 + j] = re[e]; zi[g * 16 + j] = im[e];
      }
      pass_dit<16, 512, 9>(zr + g * 16, zi + g * 16, i0, tw8);
#pragma unroll
      for (int j = 0; j < 16; ++j) {
        orow[i0 + j * 512] = make_float2(zr[g * 16 + j] * sc, zi[g * 16 + j] * sc);
      }
    }
  }
}

extern "C" void kernel_launch(void* const* d_in, const int* in_sizes, int n_in,
                              void* d_out, int out_size, void* d_ws, size_t ws_size,
                              hipStream_t stream) {
  const float* x    = (const float*)d_in[0];
  const float* temb = (const float*)d_in[1];
  const float* wr   = (const float*)d_in[2];
  const float* wi   = (const float*)d_in[3];
  const float* dw   = (const float*)d_in[4];
  const float* db   = (const float*)d_in[5];
  float* out = (float*)d_out;

  char* ws = (char*)d_ws;
  float2* tw8  = (float2*)ws;                               // 32 KiB
  float2* tw16 = (float2*)(ws + 32768);                     // 16 KiB
  float2* xm   = (float2*)(ws + 65536);                     // 16 MiB
  float2* om   = (float2*)(ws + 65536 + (size_t)16777216);  // 16 MiB

  hipLaunchKernelGGL(init_tw_k, dim3(16), dim3(256), 0, stream, tw8, tw16);
  hipLaunchKernelGGL(fwd_fft_k, dim3(NB * CIN), dim3(256), 0, stream,
                     x, temb, dw, db, tw8, tw16, xm);
  hipLaunchKernelGGL(spec_mul_k, dim3(MODES / 16, COUT / 8), dim3(256), 0, stream,
                     xm, wr, wi, om);
  hipLaunchKernelGGL(inv_fft_k, dim3(NB * COUT), dim3(256), 0, stream,
                     om, tw8, tw16, out);
}

// Round 5
// 243.520 us; speedup vs baseline: 1.0867x; 1.0452x over previous
//
#include <hip/hip_runtime.h>
#include <math.h>

#define NB    16
#define CIN   64
#define COUT  64
#define NN    16384
#define HH    8192
#define MODES 2048
#define TEMBD 512

// XOR bank swizzle: bijection on [0,8192); makes stride-32 and contiguous-32
// per-thread LDS access patterns conflict-free without padding (LDS stays 64 KiB).
__device__ __forceinline__ int swz(int e) { return e ^ ((e >> 5) & 31); }
__device__ __forceinline__ int rev13(int x) { return (int)(__brev((unsigned)x) >> 19); }

// async global->LDS, 16B per lane: LDS dest = wave-uniform base + lane*16,
// global src is per-lane.
__device__ __forceinline__ void gl_lds16(const void* gsrc, void* lds) {
  __builtin_amdgcn_global_load_lds(
      (const __attribute__((address_space(1))) void*)gsrc,
      (__attribute__((address_space(3))) void*)lds, 16, 0, 0);
}

__global__ void init_tw_k(float2* __restrict__ tw8, float2* __restrict__ tw16) {
  int j = blockIdx.x * blockDim.x + threadIdx.x;
  if (j < 4096) {
    double a = (2.0 * 3.14159265358979323846 / 8192.0) * (double)j;
    tw8[j] = make_float2((float)cos(a), (float)sin(a));
  }
  if (j < 2048) {
    double a = (2.0 * 3.14159265358979323846 / 16384.0) * (double)j;
    tw16[j] = make_float2((float)cos(a), (float)sin(a));
  }
}

// In-register DIF pass: elements e_j = base + j*S (j=0..J-1), stages lh = LH_HI
// down; pbase = base mod h (constant across the pass's stages by construction).
template<int J, int S, int LH_HI>
__device__ __forceinline__ void pass_dif(float* zr, float* zi, int pbase,
                                         const float2* __restrict__ tw) {
  int lh = LH_HI;
#pragma unroll
  for (int half = J / 2; half >= 1; half >>= 1, --lh) {
#pragma unroll
    for (int blk = 0; blk < J; blk += 2 * half) {
#pragma unroll
      for (int q = 0; q < half; ++q) {
        const int j0 = blk + q, j1 = j0 + half;
        const float2 w = tw[(pbase + q * S) << (12 - lh)];
        const float ur = zr[j0], ui = zi[j0];
        const float vr = zr[j1], vi = zi[j1];
        zr[j0] = ur + vr; zi[j0] = ui + vi;
        const float br = ur - vr, bi = ui - vi;
        zr[j1] = br * w.x + bi * w.y;   // *(c - i s)
        zi[j1] = bi * w.x - br * w.y;
      }
    }
  }
}

// In-register DIT pass (e^{+i}): stages lh = LH_LO up.
template<int J, int S, int LH_LO>
__device__ __forceinline__ void pass_dit(float* zr, float* zi, int pbase,
                                         const float2* __restrict__ tw) {
  int lh = LH_LO;
#pragma unroll
  for (int half = 1; half <= J / 2; half <<= 1, ++lh) {
#pragma unroll
    for (int blk = 0; blk < J; blk += 2 * half) {
#pragma unroll
      for (int q = 0; q < half; ++q) {
        const int j0 = blk + q, j1 = j0 + half;
        const float2 w = tw[(pbase + q * S) << (12 - lh)];
        const float vr = zr[j1], vi = zi[j1];
        const float tr = vr * w.x - vi * w.y;  // *(c + i s)
        const float ti = vr * w.y + vi * w.x;
        const float ur = zr[j0], ui = zi[j0];
        zr[j0] = ur + tr; zi[j0] = ui + ti;
        zr[j1] = ur - tr; zi[j1] = ui - ti;
      }
    }
  }
}

// Forward: one block per (b, c_in) row. Pack-trick rfft via 8192-pt complex DIF
// FFT: 3 register passes (4+4+5 stages), 3 LDS round-trips. Fused temb scalar.
__global__ __launch_bounds__(256) void fwd_fft_k(
    const float* __restrict__ x, const float* __restrict__ temb,
    const float* __restrict__ dw, const float* __restrict__ db,
    const float2* __restrict__ tw8, const float2* __restrict__ tw16,
    float2* __restrict__ xm)
{
  __shared__ float re[HH];
  __shared__ float im[HH];
  const int row = blockIdx.x;          // b*64 + ci
  const int b = row >> 6, ci = row & 63;
  const int tid = threadIdx.x;

  // t = silu(temb[b]) . dw[ci] + db[ci]  (block-cooperative 512-dot)
  float part = 0.f;
  {
    const float* tb = temb + b * TEMBD;
    const float* wrow = dw + ci * TEMBD;
    for (int j = tid; j < TEMBD; j += 256) {
      float v = tb[j];
      part += v * wrow[j] / (1.f + __expf(-v));
    }
    for (int off = 32; off > 0; off >>= 1) part += __shfl_down(part, off, 64);
    if ((tid & 63) == 0) re[tid >> 6] = part;
  }
  __syncthreads();
  const float tval = re[0] + re[1] + re[2] + re[3] + db[ci];
  __syncthreads();

  float zr[32], zi[32];

  // P1: global (packed z[m] = x[2m] + i x[2m+1]) -> regs, stages lh=12..9, -> LDS
  const float2* xr = (const float2*)(x + (size_t)row * NN);
#pragma unroll
  for (int g = 0; g < 2; ++g) {
    const int i0 = tid + g * 256;
#pragma unroll
    for (int j = 0; j < 16; ++j) {
      float2 v = xr[i0 + j * 512];
      zr[g * 16 + j] = v.x; zi[g * 16 + j] = v.y;
    }
  }
#pragma unroll
  for (int g = 0; g < 2; ++g) {
    const int i0 = tid + g * 256;
    pass_dif<16, 512, 12>(zr + g * 16, zi + g * 16, i0, tw8);
#pragma unroll
    for (int j = 0; j < 16; ++j) {
      const int e = swz(i0 + j * 512);
      re[e] = zr[g * 16 + j]; im[e] = zi[g * 16 + j];
    }
  }
  __syncthreads();

  // P2: stride-32 groups, stages lh=8..5
  {
    const int r = tid & 31;
#pragma unroll
    for (int g = 0; g < 2; ++g) {
      const int base = ((tid >> 5) + g * 8) * 512 + r;
#pragma unroll
      for (int j = 0; j < 16; ++j) {
        const int e = swz(base + j * 32);
        zr[g * 16 + j] = re[e]; zi[g * 16 + j] = im[e];
      }
      pass_dif<16, 32, 8>(zr + g * 16, zi + g * 16, r, tw8);
#pragma unroll
      for (int j = 0; j < 16; ++j) {
        const int e = swz(base + j * 32);
        re[e] = zr[g * 16 + j]; im[e] = zi[g * 16 + j];
      }
    }
  }
  __syncthreads();

  // P3: contiguous-32 groups, stages lh=4..0. The unpack phase only reads
  // logical positions ≡0,3 (mod 4) (rev13(k)&3==0 for k<2048, ==3 for H-k),
  // so skip the other stores; DCE then deletes the dead last-stage work.
  {
    const int base = tid * 32;
#pragma unroll
    for (int j = 0; j < 32; ++j) {
      const int e = swz(base + j);
      zr[j] = re[e]; zi[j] = im[e];
    }
    pass_dif<32, 1, 4>(zr, zi, 0, tw8);
#pragma unroll
    for (int j = 0; j < 32; ++j) {
      if ((j & 3) == 1 || (j & 3) == 2) continue;
      const int e = swz(base + j);
      re[e] = zr[j]; im[e] = zi[j];
    }
  }
  __syncthreads();

  // unpack X[k] = 0.5(A+conj(B)) - 0.5 i e^{-2pi i k/N} (A-conj(B)); A=Zf[k], B=Zf[H-k]
  float2* xrow = xm + (size_t)row * MODES;
  for (int k = tid; k < MODES; k += 256) {
    const int ka = swz(rev13(k));
    const int kb = swz(rev13((HH - k) & (HH - 1)));
    float Ar = re[ka], Ai = im[ka];
    float Br = re[kb], Bi = -im[kb];
    float Sr = 0.5f * (Ar + Br), Si = 0.5f * (Ai + Bi);
    float Dr = 0.5f * (Ar - Br), Di = 0.5f * (Ai - Bi);
    float2 wv = tw16[k];
    float c = wv.x, s = wv.y;
    float Xr = Sr - s * Dr + c * Di;
    float Xi = Si - s * Di - c * Dr;
    xrow[k] = make_float2(Xr + tval, Xi);
  }
}

// out_m[b,o,m] = sum_i xm[b,i,m] * (wr[i,o,m] + i wi[i,o,m])
//
// R4 post-mortem fixes: (1) og is the FAST lane index so w-plane ds_reads are
// phase-contiguous (bank-conflict-free; R4's mm-fast mapping was 4-way);
// (2) xs double-buffered + w reg-prefetch (T14): global latency for chunk ic+1
// is issued before compute of chunk ic, never exposed between barrier and use.
// LDS 40 KiB -> 4 blocks/CU = 16 waves/CU. Tile 16b x 8o x 16m; thread =
// (og 0..3, mm 0..15, h 0..3) computes 4b x 2o x 1m.
__global__ __launch_bounds__(256) void spec_mul_k(
    const float2* __restrict__ xm, const float* __restrict__ wr,
    const float* __restrict__ wi, float2* __restrict__ om)
{
  __shared__ float2 xs[2][128 * 16];  // [buf][b*8+il][mm]       2 x 16 KiB
  __shared__ float2 wsr[8 * 16 * 4];  // [il][mm][og] {o_even,o_odd}  4 KiB
  __shared__ float2 wsi[8 * 16 * 4];  //                              4 KiB

  const int tid = threadIdx.x;
  const int og = tid & 3;             // fast: phase-contiguous LDS reads
  const int mm = (tid >> 2) & 15;
  const int h  = tid >> 6;            // wave id = b-quad
  const int ln = tid & 63;

  const int m0 = blockIdx.x * 16;
  const int o0 = blockIdx.y * 8;

  float2 acc[4][2];
#pragma unroll
  for (int j = 0; j < 4; ++j) {
    acc[j][0] = make_float2(0.f, 0.f);
    acc[j][1] = make_float2(0.f, 0.f);
  }

  float2 pr[2], pi[2];   // w prefetch regs: {wr(o_even),wr(o_odd)} per t

#define STAGE_X(ic, buf)                                                      \
  {                                                                           \
    _Pragma("unroll")                                                         \
    for (int t = 0; t < 4; ++t) {                                             \
      const int r = h * 32 + t * 8 + (ln >> 3);                               \
      const int b = r >> 3, il = r & 7;                                       \
      const float2* src =                                                     \
          xm + ((size_t)(b * CIN + (ic) * 8 + il)) * MODES + m0 + (ln & 7) * 2;\
      gl_lds16((const void*)src,                                              \
               (void*)((char*)&xs[buf][0] + (h * 32 + t * 8) * 128));         \
    }                                                                         \
  }

  // global w loads: fm-fast lane map (coalesced 64-B segments) into regs.
#define W_LOAD(ic)                                                            \
  {                                                                           \
    _Pragma("unroll")                                                         \
    for (int t = 0; t < 2; ++t) {                                             \
      const int f = tid + t * 256;                                            \
      const int fm = f & 15, fg = (f >> 4) & 3, fil = f >> 6;                 \
      const size_t rA =                                                       \
          ((size_t)(((ic) * 8 + fil) * COUT + o0 + fg * 2)) * MODES + m0 + fm;\
      pr[t] = make_float2(wr[rA], wr[rA + MODES]);                            \
      pi[t] = make_float2(wi[rA], wi[rA + MODES]);                            \
    }                                                                         \
  }

#define W_WRITE()                                                             \
  {                                                                           \
    _Pragma("unroll")                                                         \
    for (int t = 0; t < 2; ++t) {                                             \
      const int f = tid + t * 256;                                            \
      const int fm = f & 15, fg = (f >> 4) & 3, fil = f >> 6;                 \
      wsr[(fil * 16 + fm) * 4 + fg] = pr[t];                                  \
      wsi[(fil * 16 + fm) * 4 + fg] = pi[t];                                  \
    }                                                                         \
  }

#define COMPUTE(buf)                                                          \
  {                                                                           \
    _Pragma("unroll")                                                         \
    for (int il = 0; il < 8; ++il) {                                          \
      const float2 wrp = wsr[(il * 16 + mm) * 4 + og];                        \
      const float2 wip = wsi[(il * 16 + mm) * 4 + og];                        \
      _Pragma("unroll")                                                       \
      for (int j = 0; j < 4; ++j) {                                           \
        const float2 xv = xs[buf][((h * 4 + j) * 8 + il) * 16 + mm];          \
        acc[j][0].x += xv.x * wrp.x - xv.y * wip.x;                           \
        acc[j][0].y += xv.x * wip.x + xv.y * wrp.x;                           \
        acc[j][1].x += xv.x * wrp.y - xv.y * wip.y;                           \
        acc[j][1].y += xv.x * wip.y + xv.y * wrp.y;                           \
      }                                                                       \
    }                                                                         \
  }

  // prologue: fill buf 0 + w chunk 0
  STAGE_X(0, 0);
  W_LOAD(0);
  W_WRITE();
  __syncthreads();

#pragma unroll 1
  for (int ic = 0; ic < 7; ++ic) {
    const int buf = ic & 1;
    STAGE_X(ic + 1, buf ^ 1);  // async gl_lds into other buffer
    W_LOAD(ic + 1);            // issue w global loads early (T14)
    COMPUTE(buf);
    __syncthreads();           // waves done reading wsr; drains vmcnt
    W_WRITE();                 // regs -> wsr/wsi for next chunk
    __syncthreads();           // wsr + xs[buf^1] ready
  }
  COMPUTE(1);                  // ic = 7 lives in buf 1

#pragma unroll
  for (int j = 0; j < 4; ++j) {
    const int b = h * 4 + j;
    const size_t ob = ((size_t)(b * COUT + o0 + og * 2)) * MODES + m0 + mm;
    om[ob] = acc[j][0];
    om[ob + MODES] = acc[j][1];
  }
#undef STAGE_X
#undef W_LOAD
#undef W_WRITE
#undef COMPUTE
}

// Inverse: one block per (b, c_out) row. Packed half-spectrum scatter (bit-rev
// positions), then 3 register DIT passes; pass 3 stores straight to global.
__global__ __launch_bounds__(256) void inv_fft_k(
    const float2* __restrict__ om, const float2* __restrict__ tw8,
    const float2* __restrict__ tw16, float* __restrict__ out)
{
  __shared__ float re[HH];
  __shared__ float im[HH];
  const int row = blockIdx.x;   // b*64 + o
  const int tid = threadIdx.x;

  for (int q = tid; q < HH; q += 256) { re[q] = 0.f; im[q] = 0.f; }
  __syncthreads();

  const float2* grow = om + (size_t)row * MODES;
  for (int k = tid; k < MODES; k += 256) {
    float2 g = grow[k];
    if (k == 0) {
      float v = 0.5f * g.x;        // Zb[0] = 0.5*Re(G0)*(1+i)
      re[0] = v; im[0] = v;
    } else {
      // P = 0.5 G[k]; s = i w P, w = e^{+2pi i k/N}; Zb[k]=P+s, Zb[H-k]=conj(P-s)
      float2 wv = tw16[k];
      float Pr = 0.5f * g.x, Pi = 0.5f * g.y;
      float c = wv.x, s = wv.y;
      float sr = -(c * Pi + s * Pr);
      float si =  (c * Pr - s * Pi);
      int ka = swz(rev13(k));
      int kb = swz(rev13(HH - k));
      re[ka] = Pr + sr; im[ka] = Pi + si;
      re[kb] = Pr - sr; im[kb] = -(Pi - si);
    }
  }
  __syncthreads();

  float zr[32], zi[32];

  // P1: contiguous-32 groups, stages lh=0..4
  {
    const int base = tid * 32;
#pragma unroll
    for (int j = 0; j < 32; ++j) {
      const int e = swz(base + j);
      zr[j] = re[e]; zi[j] = im[e];
    }
    pass_dit<32, 1, 0>(zr, zi, 0, tw8);
#pragma unroll
    for (int j = 0; j < 32; ++j) {
      const int e = swz(base + j);
      re[e] = zr[j]; im[e] = zi[j];
    }
  }
  __syncthreads();

  // P2: stride-32 groups, stages lh=5..8
  {
    const int r = tid & 31;
#pragma unroll
    for (int g = 0; g < 2; ++g) {
      const int base = ((tid >> 5) + g * 8) * 512 + r;
#pragma unroll
      for (int j = 0; j < 16; ++j) {
        const int e = swz(base + j * 32);
        zr[g * 16 + j] = re[e]; zi[g * 16 + j] = im[e];
      }
      pass_dit<16, 32, 5>(zr + g * 16, zi + g * 16, r, tw8);
#pragma unroll
      for (int j = 0; j < 16; ++j) {
        const int e = swz(base + j * 32);
        re[e] = zr[g * 16 + j]; im[e] = zi[g * 16 + j];
      }
    }
  }
  __syncthreads();

  // P3: stride-512 groups, stages lh=9..12; write x[2m],x[2m+1] as float2
  {
    float2* orow = (float2*)(out + (size_t)row * NN);
    const float sc = 1.0f / 8192.0f;
#pragma unroll
    for (int g = 0; g < 2; ++g) {
      const int i0 = tid + g * 256;
#pragma unroll
      for (int j = 0; j < 16; ++j) {
        const int e = swz(i0 + j * 512);
        zr[g * 16 + j] = re[e]; zi[g * 16 + j] = im[e];
      }
      pass_dit<16, 512, 9>(zr + g * 16, zi + g * 16, i0, tw8);
#pragma unroll
      for (int j = 0; j < 16; ++j) {
        orow[i0 + j * 512] = make_float2(zr[g * 16 + j] * sc, zi[g * 16 + j] * sc);
      }
    }
  }
}

extern "C" void kernel_launch(void* const* d_in, const int* in_sizes, int n_in,
                              void* d_out, int out_size, void* d_ws, size_t ws_size,
                              hipStream_t stream) {
  const float* x    = (const float*)d_in[0];
  const float* temb = (const float*)d_in[1];
  const float* wr   = (const float*)d_in[2];
  const float* wi   = (const float*)d_in[3];
  const float* dw   = (const float*)d_in[4];
  const float* db   = (const float*)d_in[5];
  float* out = (float*)d_out;

  char* ws = (char*)d_ws;
  float2* tw8  = (float2*)ws;                               // 32 KiB
  float2* tw16 = (float2*)(ws + 32768);                     // 16 KiB
  float2* xm   = (float2*)(ws + 65536);                     // 16 MiB
  float2* om   = (float2*)(ws + 65536 + (size_t)16777216);  // 16 MiB

  hipLaunchKernelGGL(init_tw_k, dim3(16), dim3(256), 0, stream, tw8, tw16);
  hipLaunchKernelGGL(fwd_fft_k, dim3(NB * CIN), dim3(256), 0, stream,
                     x, temb, dw, db, tw8, tw16, xm);
  hipLaunchKernelGGL(spec_mul_k, dim3(MODES / 16, COUT / 8), dim3(256), 0, stream,
                     xm, wr, wi, om);
  hipLaunchKernelGGL(inv_fft_k, dim3(NB * COUT), dim3(256), 0, stream,
                     om, tw8, tw16, out);
}